// Round 6
// baseline (241.207 us; speedup 1.0000x reference)
//
#include <hip/hip_runtime.h>
#include <cstdint>
#include <cstddef>

#define B_    8
#define N_    2048
#define FIN   128
#define FOUT  64
#define ALPHA 0.2f
#define LOG2E 1.4426950408889634f

typedef __attribute__((ext_vector_type(8))) _Float16 half8;
typedef __attribute__((ext_vector_type(4))) _Float16 half4;
typedef __attribute__((ext_vector_type(4))) float float4v;

// ---------------------------------------------------------------------------
// Kernel 1 (fused): per block (b, r0..r0+31):
//   (a) wh = x @ W via MFMA 16x16x32 f16, split-fp16 compensation
//       (acc = ah*bh + ah*bl + al*bh -> fp32-level accuracy).
//       B-fragments built inline from fp32 W (k0 + WtG round-trip deleted).
//   (b) s1 = wh@a1, s2 = wh@a2 (fp32), whT[b][f][j] fp16.
//   (c) pack this block's 32 adj rows -> bitmask (kp fused; the 134 MB adj
//       stream overlaps other blocks' MFMA; one fewer dispatch).
// ---------------------------------------------------------------------------
__global__ __launch_bounds__(256, 2) void k1_wh(
    const float* __restrict__ x, const float* __restrict__ W,
    const float* __restrict__ w2, const int* __restrict__ adj,
    _Float16* __restrict__ whT, float* __restrict__ s1, float* __restrict__ s2,
    unsigned long long* __restrict__ maskp)
{
    __shared__ __attribute__((aligned(16))) _Float16 xth[32][136];
    __shared__ __attribute__((aligned(16))) _Float16 xtl[32][136];
    __shared__ float s1p[4][32];
    __shared__ float s2p[4][32];

    int t = threadIdx.x, lane = t & 63, w = t >> 6;
    int b = blockIdx.x >> 6;
    int r0 = (blockIdx.x & 63) << 5;          // 32 rows per block
    const float* xb = x + ((size_t)b * N_ + r0) * FIN;

    // --- stage x tile (32x128 fp32 = 16 KB), split to fp16 hi/lo ---
    #pragma unroll
    for (int j = 0; j < 4; ++j) {
        int idx = t + j * 256;
        int row = idx >> 5;
        int k0 = (idx & 31) * 4;
        float4 v = ((const float4*)xb)[idx];
        float vv[4] = {v.x, v.y, v.z, v.w};
        half4 h, l;
        #pragma unroll
        for (int e = 0; e < 4; ++e) {
            _Float16 hi = (_Float16)vv[e];
            h[e] = hi;
            l[e] = (_Float16)(vv[e] - (float)hi);
        }
        *(half4*)&xth[row][k0] = h;
        *(half4*)&xtl[row][k0] = l;
    }
    __syncthreads();

    int l15 = lane & 15, quad = lane >> 4;
    int f0 = w * 16;

    // B fragments inline from fp32 W (L2-hot, 32 KB): k = c*32 + quad*8 + e
    half8 bh[4], bl[4];
    const float* wcol = W + (f0 + l15);
    #pragma unroll
    for (int c = 0; c < 4; ++c) {
        #pragma unroll
        for (int e = 0; e < 8; ++e) {
            float v = wcol[(size_t)(c * 32 + quad * 8 + e) * FOUT];
            _Float16 hi = (_Float16)v;
            bh[c][e] = hi;
            bl[c][e] = (_Float16)(v - (float)hi);
        }
    }
    float a1f = w2[f0 + l15], a2f = w2[FOUT + f0 + l15];

    #pragma unroll
    for (int rt = 0; rt < 2; ++rt) {
        float4v acc = {0.f, 0.f, 0.f, 0.f};
        #pragma unroll
        for (int c = 0; c < 4; ++c) {
            half8 ah = *(const half8*)&xth[rt * 16 + l15][c * 32 + quad * 8];
            half8 al = *(const half8*)&xtl[rt * 16 + l15][c * 32 + quad * 8];
            acc = __builtin_amdgcn_mfma_f32_16x16x32_f16(ah, bh[c], acc, 0, 0, 0);
            acc = __builtin_amdgcn_mfma_f32_16x16x32_f16(ah, bl[c], acc, 0, 0, 0);
            acc = __builtin_amdgcn_mfma_f32_16x16x32_f16(al, bh[c], acc, 0, 0, 0);
        }
        half4 hv;
        #pragma unroll
        for (int reg = 0; reg < 4; ++reg) hv[reg] = (_Float16)acc[reg];
        *(half4*)(whT + ((size_t)b * FOUT + f0 + l15) * N_ + r0 + rt * 16 + quad * 4) = hv;

        #pragma unroll
        for (int reg = 0; reg < 4; ++reg) {
            float v1 = acc[reg] * a1f;
            float v2 = acc[reg] * a2f;
            #pragma unroll
            for (int m = 1; m <= 8; m <<= 1) {
                v1 += __shfl_xor(v1, m);
                v2 += __shfl_xor(v2, m);
            }
            if (l15 == 0) {
                s1p[w][rt * 16 + quad * 4 + reg] = v1;
                s2p[w][rt * 16 + quad * 4 + reg] = v2;
            }
        }
    }
    __syncthreads();
    if (t < 32) {
        float v = s1p[0][t] + s1p[1][t] + s1p[2][t] + s1p[3][t];
        s1[(size_t)b * N_ + r0 + t] = v;
    } else if (t < 64) {
        int r = t - 32;
        float v = s2p[0][r] + s2p[1][r] + s2p[2][r] + s2p[3][r];
        s2[(size_t)b * N_ + r0 + r] = v;
    }

    // --- (c) pack this block's 32 adj rows -> bitmask (wave w: 8 rows) ---
    size_t growbase = (size_t)b * N_ + r0 + (size_t)w * 8;
    #pragma unroll 1
    for (int r = 0; r < 8; ++r) {
        const int* rp = adj + (growbase + r) * N_ + lane;
        unsigned long long* orow = maskp + (growbase + r) * 32;
        int a[32];
        #pragma unroll
        for (int it = 0; it < 32; ++it) a[it] = rp[it * 64];  // 32 loads in flight
        #pragma unroll
        for (int it = 0; it < 32; ++it) {
            unsigned long long m = __ballot(a[it] > 0);
            if (lane == 0) orow[it] = m;
        }
    }
}

// ---------------------------------------------------------------------------
// Kernel 2: flash-style masked softmax + PV on the 4 MB bitmask (L2-hot).
// Manual 2-chunk software pipeline, NAMED register stages (no dynamic reg
// indexing): mask/s2(c+1) issued one chunk ahead; bf(c) issued at loop top
// (cover = PCOMP + barrier); fixed pT[0]/pT[1] buffers, 2 barriers per
// 2 chunks (WAR-safe: every pT re-write is preceded by a barrier that all
// readers crossed). Live set ~95 VGPR -> no spill at (256,4).
// pT stride 264: A-read bank group 4*(l15+quad) mod 32, structural-min.
// ---------------------------------------------------------------------------
__global__ __launch_bounds__(256, 4) void k2_attn(
    const unsigned* __restrict__ mask32, const _Float16* __restrict__ whT,
    const float* __restrict__ s1, const float* __restrict__ s2,
    float* __restrict__ out)
{
    __shared__ __attribute__((aligned(16))) _Float16 pT[2][16][264];    // 16.5 KB
    __shared__ float lL[16];
    __shared__ float smaxL[4];

    int t = threadIdx.x, lane = t & 63, w = t >> 6;
    int b = blockIdx.x >> 7;
    int i0 = (blockIdx.x & 127) << 4;

    // --- exact S2MAX over batch b (8 KB, L2-hot) ---
    const float4* s2v = (const float4*)(s2 + (size_t)b * N_);
    float4 ua_ = s2v[t], ub_ = s2v[t + 256];
    float vm = fmaxf(fmaxf(fmaxf(ua_.x, ua_.y), fmaxf(ua_.z, ua_.w)),
                     fmaxf(fmaxf(ub_.x, ub_.y), fmaxf(ub_.z, ub_.w)));
    #pragma unroll
    for (int m = 32; m >= 1; m >>= 1) vm = fmaxf(vm, __shfl_xor(vm, m));
    if (lane == 0) smaxL[w] = vm;
    __syncthreads();
    float s2max = fmaxf(fmaxf(smaxL[0], smaxL[1]), fmaxf(smaxL[2], smaxL[3]));

    int l15 = lane & 15, quad = lane >> 4;
    int f0 = w * 16;
    int shn = (lane & 7) * 4;

    // per-row folded constants (wave w owns rows w*4..w*4+3)
    float c1[4], c2[4], lacc[4];
    #pragma unroll
    for (int rr = 0; rr < 4; ++rr) {
        float sv = s1[(size_t)b * N_ + i0 + w * 4 + rr];   // wave-uniform
        float mm = sv + s2max;
        float mh = fmaxf(mm, ALPHA * mm);    // leaky(s1_i + s2max) >= row max
        c1[rr] = (sv - mh) * LOG2E;
        c2[rr] = (ALPHA * sv - mh) * LOG2E;
        lacc[rr] = 0.f;
    }

    const unsigned* mB = mask32 + ((size_t)b * N_ + i0 + w * 4) * 64 + (lane >> 3);
    const float* s2L = s2 + (size_t)b * N_ + lane * 4;
    const _Float16* wB = whT + ((size_t)b * FOUT + f0 + l15) * N_ + quad * 8;

    float4v acc = {0.f, 0.f, 0.f, 0.f};

    unsigned mb0[4], mb1[4];
    float4 sv0, sv1;
    half8 bfr[8];

#define LOADMS(cc, MB, SV) do {                                              \
        _Pragma("unroll")                                                    \
        for (int rr_ = 0; rr_ < 4; ++rr_)                                    \
            MB[rr_] = mB[(size_t)rr_ * 64 + (cc) * 8];                       \
        SV = *(const float4*)(s2L + (cc) * 256);                             \
    } while (0)

#define LOADBF(cc) do {                                                      \
        const _Float16* wp_ = wB + (cc) * 256;                               \
        _Pragma("unroll")                                                    \
        for (int kk_ = 0; kk_ < 8; ++kk_)                                    \
            bfr[kk_] = *(const half8*)(wp_ + kk_ * 32);                      \
    } while (0)

#define PCOMP(MB, SV, PB) do {                                               \
        float u_[4]  = {SV.x * LOG2E, SV.y * LOG2E, SV.z * LOG2E, SV.w * LOG2E}; \
        float ua2_[4] = {u_[0] * ALPHA, u_[1] * ALPHA, u_[2] * ALPHA, u_[3] * ALPHA}; \
        _Pragma("unroll")                                                    \
        for (int rr_ = 0; rr_ < 4; ++rr_) {                                  \
            unsigned mbits_ = (MB[rr_] >> shn) & 0xFu;                       \
            half4 pf_;                                                       \
            float ls_ = 0.f;                                                 \
            _Pragma("unroll")                                                \
            for (int e_ = 0; e_ < 4; ++e_) {                                 \
                float tt_ = fmaxf(c1[rr_] + u_[e_], c2[rr_] + ua2_[e_]);     \
                float p_ = __builtin_amdgcn_exp2f(tt_);                      \
                p_ = (mbits_ & (1u << e_)) ? p_ : 0.f;                       \
                ls_ += p_;                                                   \
                pf_[e_] = (_Float16)p_;                                      \
            }                                                                \
            lacc[rr_] += ls_;                                                \
            *(half4*)&pT[PB][w * 4 + rr_][lane * 4] = pf_;                   \
        }                                                                    \
    } while (0)

#define MFMA8(PB) do {                                                       \
        _Pragma("unroll")                                                    \
        for (int kk_ = 0; kk_ < 8; ++kk_) {                                  \
            half8 af_ = *(const half8*)&pT[PB][l15][kk_ * 32 + quad * 8];    \
            acc = __builtin_amdgcn_mfma_f32_16x16x32_f16(af_, bfr[kk_], acc, 0, 0, 0); \
        }                                                                    \
    } while (0)

    LOADMS(0, mb0, sv0);                       // prologue

    #pragma unroll 1
    for (int c = 0; c < 8; c += 2) {
        LOADBF(c);                             // bf free (last MFMA consumed it)
        LOADMS(c + 1, mb1, sv1);
        PCOMP(mb0, sv0, 0);
        __syncthreads();                       // publish pT[0]
        MFMA8(0);                              // consumes bfr(c)
        LOADBF(c + 1);
        if (c < 6) LOADMS(c + 2, mb0, sv0);
        PCOMP(mb1, sv1, 1);
        if (c == 6) {                          // publish row sums (last chunk)
            #pragma unroll
            for (int rr = 0; rr < 4; ++rr) {
                float v = lacc[rr];
                #pragma unroll
                for (int m = 32; m >= 1; m >>= 1) v += __shfl_xor(v, m);
                if (lane == 0) lL[w * 4 + rr] = v;
            }
        }
        __syncthreads();                       // publish pT[1]
        MFMA8(1);                              // consumes bfr(c+1)
    }
#undef LOADMS
#undef LOADBF
#undef PCOMP
#undef MFMA8

    // epilogue: normalize, ELU, store. D: row=quad*4+reg, col=f0+l15
    #pragma unroll
    for (int reg = 0; reg < 4; ++reg) {
        int row = quad * 4 + reg;
        float val = acc[reg] / lL[row];
        val = (val > 0.f) ? val : (__expf(val) - 1.f);   // ELU
        out[((size_t)b * N_ + i0 + row) * FOUT + f0 + l15] = val;
    }
}

// ---------------------------------------------------------------------------
extern "C" void kernel_launch(void* const* d_in, const int* in_sizes, int n_in,
                              void* d_out, int out_size, void* d_ws, size_t ws_size,
                              hipStream_t stream) {
    const float* x   = (const float*)d_in[0];
    const int*   adj = (const int*)d_in[1];
    const float* W   = (const float*)d_in[2];
    const float* w2  = (const float*)d_in[3];
    float* out = (float*)d_out;

    char* ws = (char*)d_ws;
    _Float16* whT = (_Float16*)ws;                              // 2 MiB
    float* s1  = (float*)(ws + 2097152);                        // 64 KiB
    float* s2  = (float*)(ws + 2097152 + 65536);                // 64 KiB
    unsigned long long* maskp =
        (unsigned long long*)(ws + 2097152 + 131072);           // 4 MiB

    k1_wh<<<(B_ * N_) / 32, 256, 0, stream>>>(x, W, w2, adj, whT, s1, s2, maskp);
    k2_attn<<<(B_ * N_) / 16, 256, 0, stream>>>((const unsigned*)maskp, whT, s1, s2, out);
}